// Round 1
// 700.520 us; speedup vs baseline: 1.1691x; 1.1691x over previous
//
#include <hip/hip_runtime.h>

#define WS7    7
#define SHIFT3 3
#define NHEAD  6
#define CCH    192
#define HDIM   32
#define HH56   56
#define LTOK   (HH56*HH56)      // 3136
#define NWIN   64
#define NBATCH 32
#define NWTOT  (NBATCH*NWIN)    // 2048
#define LW     49
#define MTOK   (NWTOT*LW)       // 100352

typedef unsigned short u16;
typedef unsigned int   u32;
typedef __bf16 b16;
typedef b16   b16x8 __attribute__((ext_vector_type(8)));
typedef u16   u16x8 __attribute__((ext_vector_type(8)));
typedef float f32x4 __attribute__((ext_vector_type(4)));

__device__ __forceinline__ float b2f(u16 u) {
    u32 x = ((u32)u) << 16;
    return __builtin_bit_cast(float, x);
}
__device__ __forceinline__ u16 f2b(float f) {
    u32 x = __builtin_bit_cast(u32, f);
    u32 r = x + 0x7FFFu + ((x >> 16) & 1u);
    return (u16)(r >> 16);
}
__device__ __forceinline__ float gelu_exact(float x) {
    return 0.5f * x * (1.0f + erff(x * 0.7071067811865475f));
}

// token m (window-order) -> (b, l) image order (bijection)
__device__ __forceinline__ int map_token(int m, int &b) {
    int widx = m / LW, p = m - widx * LW;
    b = widx >> 6;
    int wloc = widx & 63;
    int wh = wloc >> 3, ww = wloc & 7;
    int i = p / WS7, j = p - i * WS7;
    int gh = wh * WS7 + i + SHIFT3; if (gh >= HH56) gh -= HH56;
    int gw = ww * WS7 + j + SHIFT3; if (gw >= HH56) gw -= HH56;
    return gh * HH56 + gw;
}

// ---- dtype probe: flag=1 if x is fp32 storage, 0 if bf16 storage.
// 1024 threads, one vectorized round (16384 u16 = 32KB sample), shuffle-reduce.
// fp32 N(0,1): low-half u16s have uniform mantissa bits -> (u>>7)&0xFF >= 0xC0
// with p~=0.25 -> E[h] ~= 2048. bf16 N(0,1): exponent never >= 0xC0 -> h ~= 0.
__global__ __launch_bounds__(1024) void probe_kernel(const u16* __restrict__ x, int* flag) {
    __shared__ int ch, cz;
    if (threadIdx.x == 0) { ch = 0; cz = 0; }
    __syncthreads();
    int i = threadIdx.x * 16;
    u16x8 a = *(const u16x8*)(x + i);
    u16x8 b = *(const u16x8*)(x + i + 8);
    int h = 0, z = 0;
    #pragma unroll
    for (int q = 0; q < 8; q++) {
        h += (((a[q] >> 7) & 0xFF) >= 0xC0) + (((b[q] >> 7) & 0xFF) >= 0xC0);
        z += (a[q] == 0) + (b[q] == 0);
    }
    #pragma unroll
    for (int off = 32; off > 0; off >>= 1) {
        h += __shfl_xor(h, off, 64);
        z += __shfl_xor(z, off, 64);
    }
    if ((threadIdx.x & 63) == 0) { atomicAdd(&ch, h); atomicAdd(&cz, z); }
    __syncthreads();
    if (threadIdx.x == 0) *flag = (ch > 250 || cz > 2048) ? 1 : 0;
}

// ---- canonicalize ALL param tensors to bf16 in ONE launch (was 12 launches).
#define CANON_TOTAL 445302
__global__ __launch_bounds__(256) void canon_all_kernel(
    const int* __restrict__ flag,
    const void* s0, const void* s1, const void* s2,  const void* s3,
    const void* s4, const void* s5, const void* s6,  const void* s7,
    const void* s8, const void* s9, const void* s10, const void* s11,
    char* __restrict__ ws)
{
    int i = blockIdx.x * 256 + threadIdx.x;
    if (i >= CANON_TOTAL) return;
    const void* srcs[12] = {s0, s1, s2, s3, s4, s5, s6, s7, s8, s9, s10, s11};
    const int cnt[12] = {110592, 36864, 147456, 147456, 192, 192, 192, 192, 192, 768, 192, 1014};
    const int off[12] = {64, 221248, 294976, 589888, 884800, 885184, 885568, 885952, 886336, 886720, 888256, 888640};
    int seg = 0, base = 0;
    while (seg < 11 && i >= base + cnt[seg]) { base += cnt[seg]; seg++; }
    int j = i - base;
    const void* sp = srcs[seg];
    u16* dp = (u16*)(ws + off[seg]);
    dp[j] = (*flag) ? f2b(((const float*)sp)[j]) : ((const u16*)sp)[j];
}

// ---- LayerNorm. GATHER=1: src = d_in[0] (dtype per flag), rows via map_token.
template<int GATHER>
__global__ __launch_bounds__(256) void ln_kernel(
    const void* __restrict__ src, const u16* __restrict__ w, const u16* __restrict__ bia,
    u16* __restrict__ dst, int m_base, const int* __restrict__ flag)
{
    int wave = threadIdx.x >> 6, lane = threadIdx.x & 63;
    int mloc = blockIdx.x * 4 + wave;
    size_t row;
    if (GATHER) { int b; int l = map_token(m_base + mloc, b); row = (size_t)b * LTOK + l; }
    else row = mloc;
    float v0, v1, v2;
    if (GATHER && *flag) {
        const float* xp = (const float*)src + row * CCH;
        v0 = xp[lane]; v1 = xp[lane + 64]; v2 = xp[lane + 128];
    } else {
        const u16* xp = (const u16*)src + row * CCH;
        v0 = b2f(xp[lane]); v1 = b2f(xp[lane + 64]); v2 = b2f(xp[lane + 128]);
    }
    float s = v0 + v1 + v2, sq = v0 * v0 + v1 * v1 + v2 * v2;
    for (int off = 32; off > 0; off >>= 1) {
        s  += __shfl_xor(s, off, 64);
        sq += __shfl_xor(sq, off, 64);
    }
    float mean = s * (1.f / 192.f);
    float var  = fmaxf(sq * (1.f / 192.f) - mean * mean, 0.f);
    float rstd = rsqrtf(var + 1e-5f);
    u16* op = dst + (size_t)mloc * CCH;
    op[lane]       = f2b((v0 - mean) * rstd * b2f(w[lane])       + b2f(bia[lane]));
    op[lane + 64]  = f2b((v1 - mean) * rstd * b2f(w[lane + 64])  + b2f(bia[lane + 64]));
    op[lane + 128] = f2b((v2 - mean) * rstd * b2f(w[lane + 128]) + b2f(bia[lane + 128]));
}

// ---- DMA-stage a 64-row x 192-col bf16 tile (row stride ldg u16) into padded
// LDS [64][200] (400B rows -> stride-400 ds_read_b128 is 8-lanes/bank-group =
// conflict-optimal). LDS dest is wave-uniform base + lane*16 (HW rule), so we
// enumerate 16B chunks linearly: chunk t -> row t/25, col-chunk t%25 (chunk 24
// is the pad; its source is clamped to the row start, data unused).
__device__ __forceinline__ void stage192(const u16* __restrict__ g, int ldg, u16* s, int tid) {
    #pragma unroll
    for (int it = 0; it < 7; it++) {
        int t = it * 256 + tid;
        if (t < 1600) {                     // 64 rows * 25 chunks
            int row = t / 25, c = t - row * 25;
            int cc = (c == 24) ? 0 : c;
            const u16* src = g + (size_t)row * ldg + cc * 8;
            u16* dst = s + (size_t)(it * 256 + (tid & ~63)) * 8;   // wave base
            __builtin_amdgcn_global_load_lds(
                (const __attribute__((address_space(1))) void*)src,
                (__attribute__((address_space(3))) void*)dst, 16, 0, 0);
        }
    }
}

// ---- GEMM: D[m][n] = sum_k A[m][k]*Bm[n][k], bf16, fp32 acc, 64x64 tile.
// Full-K LDS staging: K=192 -> single stage + 2 barriers total (was 12);
// K=768 -> 4 rounds of 192 (8 barriers, was 48). 24 MFMA per barrier pair.
template<int MODE>
__global__ __launch_bounds__(256) void gemm_bt_kernel(
    const u16* __restrict__ A, const u16* __restrict__ Bm, int K, int N,
    const u16* __restrict__ bias,
    u16* __restrict__ Cb,
    u16* __restrict__ X1,
    const void* __restrict__ Xin,
    void* __restrict__ Oout, size_t o_off, int m_base,
    const int* __restrict__ flag)
{
    __shared__ __align__(16) u16 As[64 * 200];
    __shared__ __align__(16) u16 Bs[64 * 200];
    int isf = *flag;
    int tid = threadIdx.x;
    int m0 = blockIdx.x * 64, n0 = blockIdx.y * 64;
    int wave = tid >> 6, lane = tid & 63;
    int wm = wave >> 1, wn = wave & 1;
    int quad = lane >> 4, mr = lane & 15;
    f32x4 acc00 = {}, acc01 = {}, acc10 = {}, acc11 = {};

    const u16* pa0 = &As[(wm * 32 + mr) * 200 + quad * 8];
    const u16* pb0 = &Bs[(wn * 32 + mr) * 200 + quad * 8];

    for (int k0 = 0; k0 < K; k0 += 192) {
        if (k0) __syncthreads();            // protect LDS before re-stage
        stage192(A  + (size_t)m0 * K + k0, K, As, tid);
        stage192(Bm + (size_t)n0 * K + k0, K, Bs, tid);
        __syncthreads();                    // implies vmcnt(0) drain of DMA
        #pragma unroll
        for (int ks = 0; ks < 6; ks++) {
            b16x8 a0 = __builtin_bit_cast(b16x8, *(const u16x8*)(pa0 + ks * 32));
            b16x8 a1 = __builtin_bit_cast(b16x8, *(const u16x8*)(pa0 + 16 * 200 + ks * 32));
            b16x8 b0 = __builtin_bit_cast(b16x8, *(const u16x8*)(pb0 + ks * 32));
            b16x8 b1 = __builtin_bit_cast(b16x8, *(const u16x8*)(pb0 + 16 * 200 + ks * 32));
            acc00 = __builtin_amdgcn_mfma_f32_16x16x32_bf16(a0, b0, acc00, 0, 0, 0);
            acc01 = __builtin_amdgcn_mfma_f32_16x16x32_bf16(a0, b1, acc01, 0, 0, 0);
            acc10 = __builtin_amdgcn_mfma_f32_16x16x32_bf16(a1, b0, acc10, 0, 0, 0);
            acc11 = __builtin_amdgcn_mfma_f32_16x16x32_bf16(a1, b1, acc11, 0, 0, 0);
        }
    }

    f32x4 accs[2][2] = {{acc00, acc01}, {acc10, acc11}};
    for (int sm = 0; sm < 2; sm++) {
        for (int sn = 0; sn < 2; sn++) {
            f32x4 v = accs[sm][sn];
            int nn = n0 + wn * 32 + sn * 16 + mr;
            int mb = m0 + wm * 32 + sm * 16 + quad * 4;
            for (int r = 0; r < 4; r++) {
                int mm = mb + r;
                float val = v[r];
                if (MODE == 0) {
                    Cb[(size_t)mm * N + nn] = f2b(val);
                } else if (MODE == 1) {
                    val += b2f(bias[nn]);
                    int b; int l = map_token(m_base + mm, b);
                    size_t idx = ((size_t)b * LTOK + l) * CCH + nn;
                    float xi = isf ? ((const float*)Xin)[idx] : b2f(((const u16*)Xin)[idx]);
                    X1[idx] = f2b(xi + val);
                } else if (MODE == 2) {
                    val = gelu_exact(val + b2f(bias[nn]));
                    Cb[(size_t)mm * N + nn] = f2b(val);
                } else {
                    val = gelu_exact(val + b2f(bias[nn]));
                    size_t idx = (size_t)mm * CCH + nn;
                    float r2 = val + b2f(X1[idx]);
                    if (isf) ((float*)Oout)[o_off + idx] = r2;
                    else     ((u16*)Oout)[o_off + idx]  = f2b(r2);
                }
            }
        }
    }
}

// ---- MFMA attention: 1 block = 1 (window, head); 4 waves = 4 row-tiles of 64x64 S.
// Q,K row-major [tok][d]; V transposed [d][tok] with rows padded to 72 u16
// (144B stride -> conflict-optimal PV reads; 128B stride was 2x conflicted).
// V staged via 16B vector loads + LDS transpose scatter (was 2048 scalar
// global loads per block). P via LDS (rows padded to 72 as well).
__global__ __launch_bounds__(256) void attn_kernel(
    const u16* __restrict__ qkv, const u16* __restrict__ rel_bias,
    u16* __restrict__ aout)
{
    __shared__ __align__(16) u16 qs[64 * 32];
    __shared__ __align__(16) u16 ks[64 * 32];
    __shared__ __align__(16) u16 vsT[32 * 72];
    __shared__ __align__(16) u16 ps[64 * 72];
    __shared__ float bias_s[169];
    int blk = blockIdx.x;
    int widx = blk / NHEAD, head = blk - widx * NHEAD;
    int wloc = widx & 63;
    int wh = wloc >> 3, ww = wloc & 7;
    int tid = threadIdx.x;
    const u16* base = qkv + (size_t)widx * LW * 576 + head * HDIM;

    if (tid < 196) {
        int i = tid >> 2, c8 = (tid & 3) * 8;
        *(uint4*)&qs[i * 32 + c8] = *(const uint4*)(base + (size_t)i * 576 + c8);
        *(uint4*)&ks[i * 32 + c8] = *(const uint4*)(base + (size_t)i * 576 + 192 + c8);
        u16x8 vv = *(const u16x8*)(base + (size_t)i * 576 + 384 + c8);
        #pragma unroll
        for (int q = 0; q < 8; q++) vsT[(c8 + q) * 72 + i] = vv[q];
    }
    for (int idx = tid; idx < 32 * 15; idx += 256) {   // zero pad cols 49..63
        int d = idx / 15, j = 49 + (idx - d * 15);
        vsT[d * 72 + j] = 0;
    }
    if (tid < 169) bias_s[tid] = b2f(rel_bias[tid * NHEAD + head]);
    __syncthreads();

    int wave = tid >> 6, lane = tid & 63;
    int quad = lane >> 4, c = lane & 15;

    // ---- S = Q @ K^T  (row-tile mt = wave)
    b16x8 aq = __builtin_bit_cast(b16x8, *(const u16x8*)&qs[(wave * 16 + c) * 32 + quad * 8]);
    f32x4 sacc[4];
    #pragma unroll
    for (int nt = 0; nt < 4; nt++) {
        b16x8 bk = __builtin_bit_cast(b16x8, *(const u16x8*)&ks[(nt * 16 + c) * 32 + quad * 8]);
        f32x4 z = {};
        sacc[nt] = __builtin_amdgcn_mfma_f32_16x16x32_bf16(aq, bk, z, 0, 0, 0);
    }

    // ---- epilogue: scale + bias + mask, per-element (row i, col j)
    const float SCALE = 13.856406460551018f;
    float val[4][4];
    int rbase = wave * 16 + quad * 4;
    #pragma unroll
    for (int r = 0; r < 4; r++) {
        int i = rbase + r;
        int ih = i / WS7, iw = i - ih * WS7;
        int ri = (wh == 7 ? (ih < 4 ? 1 : 2) : 0) * 3 + (ww == 7 ? (iw < 4 ? 1 : 2) : 0);
        #pragma unroll
        for (int nt = 0; nt < 4; nt++) {
            int j = nt * 16 + c;
            float v;
            if (i >= LW) v = 0.f;
            else if (j >= LW) v = -1e30f;
            else {
                int jh = j / WS7, jw = j - jh * WS7;
                int rj = (wh == 7 ? (jh < 4 ? 1 : 2) : 0) * 3 + (ww == 7 ? (jw < 4 ? 1 : 2) : 0);
                if (ri != rj) v = -100.0f;
                else v = fmaf(sacc[nt][r], SCALE, bias_s[(ih - jh + 6) * 13 + (iw - jw + 6)]);
            }
            val[r][nt] = v;
        }
    }

    // ---- softmax over each row (16 lanes of same quad hold the row)
    #pragma unroll
    for (int r = 0; r < 4; r++) {
        float mx = fmaxf(fmaxf(val[r][0], val[r][1]), fmaxf(val[r][2], val[r][3]));
        for (int d = 1; d < 16; d <<= 1) mx = fmaxf(mx, __shfl_xor(mx, d, 64));
        float sum = 0.f;
        #pragma unroll
        for (int nt = 0; nt < 4; nt++) { float e = expf(val[r][nt] - mx); val[r][nt] = e; sum += e; }
        for (int d = 1; d < 16; d <<= 1) sum += __shfl_xor(sum, d, 64);
        float inv = 1.f / sum;
        int i = rbase + r;
        #pragma unroll
        for (int nt = 0; nt < 4; nt++)
            ps[i * 72 + nt * 16 + c] = f2b(val[r][nt] * inv);
    }

    // ---- O = P @ V   (own rows only; ds_write->ds_read ordered by lgkmcnt)
    f32x4 oacc[2] = {{}, {}};
    #pragma unroll
    for (int kh = 0; kh < 2; kh++) {
        b16x8 ap = __builtin_bit_cast(b16x8, *(const u16x8*)&ps[(wave * 16 + c) * 72 + kh * 32 + quad * 8]);
        #pragma unroll
        for (int nt = 0; nt < 2; nt++) {
            b16x8 bv = __builtin_bit_cast(b16x8, *(const u16x8*)&vsT[(nt * 16 + c) * 72 + kh * 32 + quad * 8]);
            oacc[nt] = __builtin_amdgcn_mfma_f32_16x16x32_bf16(ap, bv, oacc[nt], 0, 0, 0);
        }
    }
    #pragma unroll
    for (int nt = 0; nt < 2; nt++) {
        #pragma unroll
        for (int r = 0; r < 4; r++) {
            int i = rbase + r;
            if (i < LW)
                aout[((size_t)widx * LW + i) * CCH + head * HDIM + nt * 16 + c] = f2b(oacc[nt][r]);
        }
    }
}

extern "C" void kernel_launch(void* const* d_in, const int* in_sizes, int n_in,
                              void* d_out, int out_size, void* d_ws, size_t ws_size,
                              hipStream_t stream)
{
    const void* x_in = d_in[0];
    char* ws = (char*)d_ws;
    int* flag = (int*)ws;

    u16* n1w_c  = (u16*)(ws + 884800);
    u16* n1b_c  = (u16*)(ws + 885184);
    u16* n2w_c  = (u16*)(ws + 885568);
    u16* n2b_c  = (u16*)(ws + 885952);
    u16* projb_c= (u16*)(ws + 886336);
    u16* fc1b_c = (u16*)(ws + 886720);
    u16* fc2b_c = (u16*)(ws + 888256);
    u16* relb_c = (u16*)(ws + 888640);
    u16* qkvw_c = (u16*)(ws + 64);
    u16* projw_c = (u16*)(ws + 221248);
    u16* fc1w_c = (u16*)(ws + 294976);
    u16* fc2w_c = (u16*)(ws + 589888);

    const size_t P0 = 1u << 20;
    u16* x1   = (u16*)(ws + P0);
    u16* winq = (u16*)(ws + P0 + 38535168);
    u16* qkvq = (u16*)(ws + P0 + 38535168 + 9633792);
    u16* xnq  = winq;
    u16* h1q  = (u16*)(ws + P0 + 38535168 + 4816896);

    probe_kernel<<<1, 1024, 0, stream>>>((const u16*)x_in, flag);

    canon_all_kernel<<<(CANON_TOTAL + 255) / 256, 256, 0, stream>>>(
        flag,
        d_in[7], d_in[9], d_in[13], d_in[15],
        d_in[5], d_in[6], d_in[11], d_in[12],
        d_in[10], d_in[14], d_in[16], d_in[8],
        ws);

    const int M4 = MTOK / 4;   // 25088
    const int M8 = MTOK / 8;   // 12544

    for (int q = 0; q < 4; q++) {
        int mb = q * M4;
        ln_kernel<1><<<M4 / 4, 256, 0, stream>>>(x_in, n1w_c, n1b_c, winq, mb, flag);
        gemm_bt_kernel<0><<<dim3(M4 / 64, 9), 256, 0, stream>>>(
            winq, qkvw_c, 192, 576, nullptr, qkvq, nullptr, nullptr, nullptr, 0, 0, flag);
        attn_kernel<<<(NWTOT / 4) * NHEAD, 256, 0, stream>>>(qkvq, relb_c, winq);
        gemm_bt_kernel<1><<<dim3(M4 / 64, 3), 256, 0, stream>>>(
            winq, projw_c, 192, 192, projb_c, nullptr, x1, x_in, nullptr, 0, mb, flag);
    }

    for (int e = 0; e < 8; e++) {
        size_t off = (size_t)e * M8 * CCH;
        ln_kernel<0><<<M8 / 4, 256, 0, stream>>>(x1 + off, n2w_c, n2b_c, xnq, 0, flag);
        gemm_bt_kernel<2><<<dim3(M8 / 64, 12), 256, 0, stream>>>(
            xnq, fc1w_c, 192, 768, fc1b_c, h1q, nullptr, nullptr, nullptr, 0, 0, flag);
        gemm_bt_kernel<3><<<dim3(M8 / 64, 3), 256, 0, stream>>>(
            h1q, fc2w_c, 768, 192, fc2b_c, nullptr, x1 + off, nullptr, d_out, off, 0, flag);
    }
}

// Round 2
// 587.205 us; speedup vs baseline: 1.3948x; 1.1930x over previous
//
#include <hip/hip_runtime.h>

#define WS7    7
#define SHIFT3 3
#define NHEAD  6
#define CCH    192
#define HDIM   32
#define HH56   56
#define LTOK   (HH56*HH56)      // 3136
#define NWIN   64
#define NBATCH 32
#define NWTOT  (NBATCH*NWIN)    // 2048
#define LW     49
#define MTOK   (NWTOT*LW)       // 100352

typedef unsigned short u16;
typedef unsigned int   u32;
typedef __bf16 b16;
typedef b16   b16x8 __attribute__((ext_vector_type(8)));
typedef u16   u16x8 __attribute__((ext_vector_type(8)));
typedef float f32x4 __attribute__((ext_vector_type(4)));

__device__ __forceinline__ float b2f(u16 u) {
    u32 x = ((u32)u) << 16;
    return __builtin_bit_cast(float, x);
}
__device__ __forceinline__ u16 f2b(float f) {
    u32 x = __builtin_bit_cast(u32, f);
    u32 r = x + 0x7FFFu + ((x >> 16) & 1u);
    return (u16)(r >> 16);
}
__device__ __forceinline__ float gelu_exact(float x) {
    return 0.5f * x * (1.0f + erff(x * 0.7071067811865475f));
}

// token m (window-order) -> (b, l) image order (bijection)
__device__ __forceinline__ int map_token(int m, int &b) {
    int widx = m / LW, p = m - widx * LW;
    b = widx >> 6;
    int wloc = widx & 63;
    int wh = wloc >> 3, ww = wloc & 7;
    int i = p / WS7, j = p - i * WS7;
    int gh = wh * WS7 + i + SHIFT3; if (gh >= HH56) gh -= HH56;
    int gw = ww * WS7 + j + SHIFT3; if (gw >= HH56) gw -= HH56;
    return gh * HH56 + gw;
}

// ---- dtype probe: flag=1 if x is fp32 storage, 0 if bf16 storage.
__global__ __launch_bounds__(1024) void probe_kernel(const u16* __restrict__ x, int* flag) {
    __shared__ int ch, cz;
    if (threadIdx.x == 0) { ch = 0; cz = 0; }
    __syncthreads();
    int i = threadIdx.x * 16;
    u16x8 a = *(const u16x8*)(x + i);
    u16x8 b = *(const u16x8*)(x + i + 8);
    int h = 0, z = 0;
    #pragma unroll
    for (int q = 0; q < 8; q++) {
        h += (((a[q] >> 7) & 0xFF) >= 0xC0) + (((b[q] >> 7) & 0xFF) >= 0xC0);
        z += (a[q] == 0) + (b[q] == 0);
    }
    #pragma unroll
    for (int off = 32; off > 0; off >>= 1) {
        h += __shfl_xor(h, off, 64);
        z += __shfl_xor(z, off, 64);
    }
    if ((threadIdx.x & 63) == 0) { atomicAdd(&ch, h); atomicAdd(&cz, z); }
    __syncthreads();
    if (threadIdx.x == 0) *flag = (ch > 250 || cz > 2048) ? 1 : 0;
}

// ---- canonicalize ALL param tensors to bf16 in ONE launch.
#define CANON_TOTAL 445302
__global__ __launch_bounds__(256) void canon_all_kernel(
    const int* __restrict__ flag,
    const void* s0, const void* s1, const void* s2,  const void* s3,
    const void* s4, const void* s5, const void* s6,  const void* s7,
    const void* s8, const void* s9, const void* s10, const void* s11,
    char* __restrict__ ws)
{
    int i = blockIdx.x * 256 + threadIdx.x;
    if (i >= CANON_TOTAL) return;
    const void* srcs[12] = {s0, s1, s2, s3, s4, s5, s6, s7, s8, s9, s10, s11};
    const int cnt[12] = {110592, 36864, 147456, 147456, 192, 192, 192, 192, 192, 768, 192, 1014};
    const int off[12] = {64, 221248, 294976, 589888, 884800, 885184, 885568, 885952, 886336, 886720, 888256, 888640};
    int seg = 0, base = 0;
    while (seg < 11 && i >= base + cnt[seg]) { base += cnt[seg]; seg++; }
    int j = i - base;
    const void* sp = srcs[seg];
    u16* dp = (u16*)(ws + off[seg]);
    dp[j] = (*flag) ? f2b(((const float*)sp)[j]) : ((const u16*)sp)[j];
}

// ---- LayerNorm (gather variant only; LN2 is fused into FC1 now).
template<int GATHER>
__global__ __launch_bounds__(256) void ln_kernel(
    const void* __restrict__ src, const u16* __restrict__ w, const u16* __restrict__ bia,
    u16* __restrict__ dst, int m_base, const int* __restrict__ flag)
{
    int wave = threadIdx.x >> 6, lane = threadIdx.x & 63;
    int mloc = blockIdx.x * 4 + wave;
    size_t row;
    if (GATHER) { int b; int l = map_token(m_base + mloc, b); row = (size_t)b * LTOK + l; }
    else row = mloc;
    float v0, v1, v2;
    if (GATHER && *flag) {
        const float* xp = (const float*)src + row * CCH;
        v0 = xp[lane]; v1 = xp[lane + 64]; v2 = xp[lane + 128];
    } else {
        const u16* xp = (const u16*)src + row * CCH;
        v0 = b2f(xp[lane]); v1 = b2f(xp[lane + 64]); v2 = b2f(xp[lane + 128]);
    }
    float s = v0 + v1 + v2, sq = v0 * v0 + v1 * v1 + v2 * v2;
    for (int off = 32; off > 0; off >>= 1) {
        s  += __shfl_xor(s, off, 64);
        sq += __shfl_xor(sq, off, 64);
    }
    float mean = s * (1.f / 192.f);
    float var  = fmaxf(sq * (1.f / 192.f) - mean * mean, 0.f);
    float rstd = rsqrtf(var + 1e-5f);
    u16* op = dst + (size_t)mloc * CCH;
    op[lane]       = f2b((v0 - mean) * rstd * b2f(w[lane])       + b2f(bia[lane]));
    op[lane + 64]  = f2b((v1 - mean) * rstd * b2f(w[lane + 64])  + b2f(bia[lane + 64]));
    op[lane + 128] = f2b((v2 - mean) * rstd * b2f(w[lane + 128]) + b2f(bia[lane + 128]));
}

// ---- DMA-stage a 64-row x 192-col bf16 tile into padded LDS [64][200].
__device__ __forceinline__ void stage192(const u16* __restrict__ g, int ldg, u16* s, int tid) {
    #pragma unroll
    for (int it = 0; it < 7; it++) {
        int t = it * 256 + tid;
        if (t < 1600) {                     // 64 rows * 25 chunks
            int row = t / 25, c = t - row * 25;
            int cc = (c == 24) ? 0 : c;
            const u16* src = g + (size_t)row * ldg + cc * 8;
            u16* dst = s + (size_t)(it * 256 + (tid & ~63)) * 8;   // wave base
            __builtin_amdgcn_global_load_lds(
                (const __attribute__((address_space(1))) void*)src,
                (__attribute__((address_space(3))) void*)dst, 16, 0, 0);
        }
    }
}

// ---- in-LDS LayerNorm of the staged 64x192 A tile (rows padded to 200).
// 256 threads = 64 rows x 4 col-groups of 48. Same math as ln_kernel.
__device__ __forceinline__ void ln_lds_rows(u16* As, const u16* __restrict__ w,
                                            const u16* __restrict__ bia, int tid) {
    int r = tid >> 2, p = tid & 3;
    u16* row = As + r * 200 + p * 48;
    u16x8 vv[6];
    float s = 0.f, sq = 0.f;
    #pragma unroll
    for (int j = 0; j < 6; j++) {
        vv[j] = *(const u16x8*)(row + j * 8);
        #pragma unroll
        for (int q = 0; q < 8; q++) { float f = b2f(vv[j][q]); s += f; sq += f * f; }
    }
    s  += __shfl_xor(s, 1, 64);  s  += __shfl_xor(s, 2, 64);
    sq += __shfl_xor(sq, 1, 64); sq += __shfl_xor(sq, 2, 64);
    float mean = s * (1.f / 192.f);
    float var  = fmaxf(sq * (1.f / 192.f) - mean * mean, 0.f);
    float rstd = rsqrtf(var + 1e-5f);
    #pragma unroll
    for (int j = 0; j < 6; j++) {
        u16x8 o;
        #pragma unroll
        for (int q = 0; q < 8; q++) {
            int col = p * 48 + j * 8 + q;
            o[q] = f2b((b2f(vv[j][q]) - mean) * rstd * b2f(w[col]) + b2f(bia[col]));
        }
        *(u16x8*)(row + j * 8) = o;
    }
}

// ---- GEMM K=192: A tile staged ONCE, NT 64-wide n-tiles streamed through a
// double-buffered B stage. 24 MFMA per barrier, 1 barrier per n-tile.
// MODE 0: C=A*B^T (qkv).  MODE 1: proj + residual scatter into x1.
// MODE 2: fc1 + gelu, LNF=1 applies LayerNorm to A in LDS first.
template<int MODE, int NT, int LNF>
__global__ __launch_bounds__(256) void gemm_k192(
    const u16* __restrict__ A, const u16* __restrict__ Bm, int N,
    const u16* __restrict__ lnw, const u16* __restrict__ lnb,
    const u16* __restrict__ bias,
    u16* __restrict__ Cb, u16* __restrict__ X1, const void* __restrict__ Xin,
    int m_base, const int* __restrict__ flag)
{
    __shared__ __align__(16) u16 As[64 * 200];
    __shared__ __align__(16) u16 Bs[2][64 * 200];
    int isf = *flag;
    int tid = threadIdx.x;
    int m0 = blockIdx.x * 64;
    int wave = tid >> 6, lane = tid & 63;
    int wm = wave >> 1, wn = wave & 1;
    int quad = lane >> 4, mr = lane & 15;

    stage192(A + (size_t)m0 * 192, 192, As, tid);
    stage192(Bm, 192, Bs[0], tid);
    __syncthreads();
    if (LNF) { ln_lds_rows(As, lnw, lnb, tid); __syncthreads(); }

    const u16* pa0 = &As[(wm * 32 + mr) * 200 + quad * 8];
    #pragma unroll 1
    for (int nb = 0; nb < NT; nb++) {
        if (nb + 1 < NT)
            stage192(Bm + (size_t)(nb + 1) * 64 * 192, 192, Bs[(nb + 1) & 1], tid);
        const u16* pb0 = &Bs[nb & 1][(wn * 32 + mr) * 200 + quad * 8];
        f32x4 acc00 = {}, acc01 = {}, acc10 = {}, acc11 = {};
        #pragma unroll
        for (int ks = 0; ks < 6; ks++) {
            b16x8 a0 = __builtin_bit_cast(b16x8, *(const u16x8*)(pa0 + ks * 32));
            b16x8 a1 = __builtin_bit_cast(b16x8, *(const u16x8*)(pa0 + 16 * 200 + ks * 32));
            b16x8 b0 = __builtin_bit_cast(b16x8, *(const u16x8*)(pb0 + ks * 32));
            b16x8 b1 = __builtin_bit_cast(b16x8, *(const u16x8*)(pb0 + 16 * 200 + ks * 32));
            acc00 = __builtin_amdgcn_mfma_f32_16x16x32_bf16(a0, b0, acc00, 0, 0, 0);
            acc01 = __builtin_amdgcn_mfma_f32_16x16x32_bf16(a0, b1, acc01, 0, 0, 0);
            acc10 = __builtin_amdgcn_mfma_f32_16x16x32_bf16(a1, b0, acc10, 0, 0, 0);
            acc11 = __builtin_amdgcn_mfma_f32_16x16x32_bf16(a1, b1, acc11, 0, 0, 0);
        }
        int n0 = nb * 64;
        f32x4 accs[2][2] = {{acc00, acc01}, {acc10, acc11}};
        #pragma unroll
        for (int sm = 0; sm < 2; sm++) {
            #pragma unroll
            for (int sn = 0; sn < 2; sn++) {
                f32x4 v = accs[sm][sn];
                int nn = n0 + wn * 32 + sn * 16 + mr;
                int mb = m0 + wm * 32 + sm * 16 + quad * 4;
                #pragma unroll
                for (int r = 0; r < 4; r++) {
                    int mm = mb + r;
                    float val = v[r];
                    if (MODE == 0) {
                        Cb[(size_t)mm * N + nn] = f2b(val);
                    } else if (MODE == 1) {
                        val += b2f(bias[nn]);
                        int b; int l = map_token(m_base + mm, b);
                        size_t idx = ((size_t)b * LTOK + l) * CCH + nn;
                        float xi = isf ? ((const float*)Xin)[idx] : b2f(((const u16*)Xin)[idx]);
                        X1[idx] = f2b(xi + val);
                    } else {
                        val = gelu_exact(val + b2f(bias[nn]));
                        Cb[(size_t)mm * N + nn] = f2b(val);
                    }
                }
            }
        }
        __syncthreads();   // B(nb+1) DMA drained; Bs[nb&1] free for re-stage
    }
}

// ---- GEMM K=768 (fc2): per k-chunk stage A once, stream 3 B n-tiles (dbuf);
// accumulators for all 3 n-tiles live across k-chunks (48 VGPR, static idx).
// Epilogue: gelu + bias + residual(X1) -> Oout (dtype per flag).
__global__ __launch_bounds__(256) void gemm_k768(
    const u16* __restrict__ A, const u16* __restrict__ Bm,
    const u16* __restrict__ bias, const u16* __restrict__ X1,
    void* __restrict__ Oout, size_t o_off, const int* __restrict__ flag)
{
    __shared__ __align__(16) u16 As[64 * 200];
    __shared__ __align__(16) u16 Bs[2][64 * 200];
    int isf = *flag;
    int tid = threadIdx.x;
    int m0 = blockIdx.x * 64;
    int wave = tid >> 6, lane = tid & 63;
    int wm = wave >> 1, wn = wave & 1;
    int quad = lane >> 4, mr = lane & 15;

    f32x4 acc[3][4] = {};   // [nb][sm*2+sn], all indexing static via unroll

    const u16* pa0 = &As[(wm * 32 + mr) * 200 + quad * 8];
    #pragma unroll 1
    for (int k0 = 0; k0 < 768; k0 += 192) {
        stage192(A + (size_t)m0 * 768 + k0, 768, As, tid);
        stage192(Bm + k0, 768, Bs[0], tid);
        __syncthreads();
        #pragma unroll
        for (int nb = 0; nb < 3; nb++) {
            if (nb < 2)
                stage192(Bm + (size_t)(nb + 1) * 64 * 768 + k0, 768, Bs[(nb + 1) & 1], tid);
            const u16* pb0 = &Bs[nb & 1][(wn * 32 + mr) * 200 + quad * 8];
            #pragma unroll
            for (int ks = 0; ks < 6; ks++) {
                b16x8 a0 = __builtin_bit_cast(b16x8, *(const u16x8*)(pa0 + ks * 32));
                b16x8 a1 = __builtin_bit_cast(b16x8, *(const u16x8*)(pa0 + 16 * 200 + ks * 32));
                b16x8 b0 = __builtin_bit_cast(b16x8, *(const u16x8*)(pb0 + ks * 32));
                b16x8 b1 = __builtin_bit_cast(b16x8, *(const u16x8*)(pb0 + 16 * 200 + ks * 32));
                acc[nb][0] = __builtin_amdgcn_mfma_f32_16x16x32_bf16(a0, b0, acc[nb][0], 0, 0, 0);
                acc[nb][1] = __builtin_amdgcn_mfma_f32_16x16x32_bf16(a0, b1, acc[nb][1], 0, 0, 0);
                acc[nb][2] = __builtin_amdgcn_mfma_f32_16x16x32_bf16(a1, b0, acc[nb][2], 0, 0, 0);
                acc[nb][3] = __builtin_amdgcn_mfma_f32_16x16x32_bf16(a1, b1, acc[nb][3], 0, 0, 0);
            }
            __syncthreads();
        }
    }

    #pragma unroll
    for (int nb = 0; nb < 3; nb++) {
        #pragma unroll
        for (int sm = 0; sm < 2; sm++) {
            #pragma unroll
            for (int sn = 0; sn < 2; sn++) {
                f32x4 v = acc[nb][sm * 2 + sn];
                int nn = nb * 64 + wn * 32 + sn * 16 + mr;
                int mb = m0 + wm * 32 + sm * 16 + quad * 4;
                #pragma unroll
                for (int r = 0; r < 4; r++) {
                    int mm = mb + r;
                    float val = gelu_exact(v[r] + b2f(bias[nn]));
                    size_t idx = (size_t)mm * CCH + nn;
                    float r2 = val + b2f(X1[idx]);
                    if (isf) ((float*)Oout)[o_off + idx] = r2;
                    else     ((u16*)Oout)[o_off + idx]  = f2b(r2);
                }
            }
        }
    }
}

// ---- MFMA attention (unchanged from verified round-1 kernel)
__global__ __launch_bounds__(256) void attn_kernel(
    const u16* __restrict__ qkv, const u16* __restrict__ rel_bias,
    u16* __restrict__ aout)
{
    __shared__ __align__(16) u16 qs[64 * 32];
    __shared__ __align__(16) u16 ks[64 * 32];
    __shared__ __align__(16) u16 vsT[32 * 72];
    __shared__ __align__(16) u16 ps[64 * 72];
    __shared__ float bias_s[169];
    int blk = blockIdx.x;
    int widx = blk / NHEAD, head = blk - widx * NHEAD;
    int wloc = widx & 63;
    int wh = wloc >> 3, ww = wloc & 7;
    int tid = threadIdx.x;
    const u16* base = qkv + (size_t)widx * LW * 576 + head * HDIM;

    if (tid < 196) {
        int i = tid >> 2, c8 = (tid & 3) * 8;
        *(uint4*)&qs[i * 32 + c8] = *(const uint4*)(base + (size_t)i * 576 + c8);
        *(uint4*)&ks[i * 32 + c8] = *(const uint4*)(base + (size_t)i * 576 + 192 + c8);
        u16x8 vv = *(const u16x8*)(base + (size_t)i * 576 + 384 + c8);
        #pragma unroll
        for (int q = 0; q < 8; q++) vsT[(c8 + q) * 72 + i] = vv[q];
    }
    for (int idx = tid; idx < 32 * 15; idx += 256) {   // zero pad cols 49..63
        int d = idx / 15, j = 49 + (idx - d * 15);
        vsT[d * 72 + j] = 0;
    }
    if (tid < 169) bias_s[tid] = b2f(rel_bias[tid * NHEAD + head]);
    __syncthreads();

    int wave = tid >> 6, lane = tid & 63;
    int quad = lane >> 4, c = lane & 15;

    b16x8 aq = __builtin_bit_cast(b16x8, *(const u16x8*)&qs[(wave * 16 + c) * 32 + quad * 8]);
    f32x4 sacc[4];
    #pragma unroll
    for (int nt = 0; nt < 4; nt++) {
        b16x8 bk = __builtin_bit_cast(b16x8, *(const u16x8*)&ks[(nt * 16 + c) * 32 + quad * 8]);
        f32x4 z = {};
        sacc[nt] = __builtin_amdgcn_mfma_f32_16x16x32_bf16(aq, bk, z, 0, 0, 0);
    }

    const float SCALE = 13.856406460551018f;
    float val[4][4];
    int rbase = wave * 16 + quad * 4;
    #pragma unroll
    for (int r = 0; r < 4; r++) {
        int i = rbase + r;
        int ih = i / WS7, iw = i - ih * WS7;
        int ri = (wh == 7 ? (ih < 4 ? 1 : 2) : 0) * 3 + (ww == 7 ? (iw < 4 ? 1 : 2) : 0);
        #pragma unroll
        for (int nt = 0; nt < 4; nt++) {
            int j = nt * 16 + c;
            float v;
            if (i >= LW) v = 0.f;
            else if (j >= LW) v = -1e30f;
            else {
                int jh = j / WS7, jw = j - jh * WS7;
                int rj = (wh == 7 ? (jh < 4 ? 1 : 2) : 0) * 3 + (ww == 7 ? (jw < 4 ? 1 : 2) : 0);
                if (ri != rj) v = -100.0f;
                else v = fmaf(sacc[nt][r], SCALE, bias_s[(ih - jh + 6) * 13 + (iw - jw + 6)]);
            }
            val[r][nt] = v;
        }
    }

    #pragma unroll
    for (int r = 0; r < 4; r++) {
        float mx = fmaxf(fmaxf(val[r][0], val[r][1]), fmaxf(val[r][2], val[r][3]));
        for (int d = 1; d < 16; d <<= 1) mx = fmaxf(mx, __shfl_xor(mx, d, 64));
        float sum = 0.f;
        #pragma unroll
        for (int nt = 0; nt < 4; nt++) { float e = expf(val[r][nt] - mx); val[r][nt] = e; sum += e; }
        for (int d = 1; d < 16; d <<= 1) sum += __shfl_xor(sum, d, 64);
        float inv = 1.f / sum;
        int i = rbase + r;
        #pragma unroll
        for (int nt = 0; nt < 4; nt++)
            ps[i * 72 + nt * 16 + c] = f2b(val[r][nt] * inv);
    }

    f32x4 oacc[2] = {{}, {}};
    #pragma unroll
    for (int kh = 0; kh < 2; kh++) {
        b16x8 ap = __builtin_bit_cast(b16x8, *(const u16x8*)&ps[(wave * 16 + c) * 72 + kh * 32 + quad * 8]);
        #pragma unroll
        for (int nt = 0; nt < 2; nt++) {
            b16x8 bv = __builtin_bit_cast(b16x8, *(const u16x8*)&vsT[(nt * 16 + c) * 72 + kh * 32 + quad * 8]);
            oacc[nt] = __builtin_amdgcn_mfma_f32_16x16x32_bf16(ap, bv, oacc[nt], 0, 0, 0);
        }
    }
    #pragma unroll
    for (int nt = 0; nt < 2; nt++) {
        #pragma unroll
        for (int r = 0; r < 4; r++) {
            int i = rbase + r;
            if (i < LW)
                aout[((size_t)widx * LW + i) * CCH + head * HDIM + nt * 16 + c] = f2b(oacc[nt][r]);
        }
    }
}

extern "C" void kernel_launch(void* const* d_in, const int* in_sizes, int n_in,
                              void* d_out, int out_size, void* d_ws, size_t ws_size,
                              hipStream_t stream)
{
    const void* x_in = d_in[0];
    char* ws = (char*)d_ws;
    int* flag = (int*)ws;

    u16* qkvw_c  = (u16*)(ws + 64);
    u16* projw_c = (u16*)(ws + 221248);
    u16* fc1w_c  = (u16*)(ws + 294976);
    u16* fc2w_c  = (u16*)(ws + 589888);
    u16* n1w_c   = (u16*)(ws + 884800);
    u16* n1b_c   = (u16*)(ws + 885184);
    u16* n2w_c   = (u16*)(ws + 885568);
    u16* n2b_c   = (u16*)(ws + 885952);
    u16* projb_c = (u16*)(ws + 886336);
    u16* fc1b_c  = (u16*)(ws + 886720);
    u16* fc2b_c  = (u16*)(ws + 888256);
    u16* relb_c  = (u16*)(ws + 888640);

    const size_t P0 = 1u << 20;
    const size_t X1SZ   = (size_t)MTOK * CCH * 2;   //  38,535,168
    const size_t QKVSZ  = (size_t)MTOK * 576 * 2;   // 115,605,504
    const size_t H1FULL = (size_t)MTOK * 768 * 2;   // 154,140,672

    u16* x1 = (u16*)(ws + P0);

    probe_kernel<<<1, 1024, 0, stream>>>((const u16*)x_in, flag);
    canon_all_kernel<<<(CANON_TOTAL + 255) / 256, 256, 0, stream>>>(
        flag,
        d_in[7], d_in[9], d_in[13], d_in[15],
        d_in[5], d_in[6], d_in[11], d_in[12],
        d_in[10], d_in[14], d_in[16], d_in[8],
        ws);

    // ---- workspace tiering: prefer un-chunked pipeline if ws is big enough.
    int QC, EC;
    u16 *winq, *qkvq, *h1q;
    if (ws_size >= P0 + 2 * X1SZ + H1FULL) {            // 232.3 MB
        QC = 1; EC = 1;
        winq = (u16*)(ws + P0 + X1SZ);
        qkvq = (u16*)(ws + P0 + 2 * X1SZ);
        h1q  = qkvq;                                    // alias: qkvq dead in MLP phase
    } else if (ws_size >= P0 + 2 * X1SZ + QKVSZ) {      // 193.7 MB
        QC = 1; EC = 2;
        winq = (u16*)(ws + P0 + X1SZ);
        qkvq = (u16*)(ws + P0 + 2 * X1SZ);
        h1q  = qkvq;                                    // half-h1 (77MB) fits in QKVSZ
    } else {                                            // proven 78.1 MB layout
        QC = 4; EC = 8;
        winq = (u16*)(ws + P0 + X1SZ);
        qkvq = (u16*)(ws + P0 + X1SZ + 9633792);
        h1q  = (u16*)(ws + P0 + X1SZ);                  // alias winq+qkvq (dead in MLP)
    }

    const int MQ = MTOK / QC;
    const int ME = MTOK / EC;

    for (int q = 0; q < QC; q++) {
        int mb = q * MQ;
        ln_kernel<1><<<MQ / 4, 256, 0, stream>>>(x_in, n1w_c, n1b_c, winq, mb, flag);
        gemm_k192<0, 9, 0><<<MQ / 64, 256, 0, stream>>>(
            winq, qkvw_c, 576, nullptr, nullptr, nullptr, qkvq, nullptr, nullptr, 0, flag);
        attn_kernel<<<(NWTOT / QC) * NHEAD, 256, 0, stream>>>(qkvq, relb_c, winq);
        gemm_k192<1, 3, 0><<<MQ / 64, 256, 0, stream>>>(
            winq, projw_c, 192, nullptr, nullptr, projb_c, nullptr, x1, x_in, mb, flag);
    }

    for (int e = 0; e < EC; e++) {
        size_t off = (size_t)e * ME * CCH;
        gemm_k192<2, 12, 1><<<ME / 64, 256, 0, stream>>>(
            x1 + off, fc1w_c, 768, n2w_c, n2b_c, fc1b_c, h1q, nullptr, nullptr, 0, flag);
        gemm_k768<<<ME / 64, 256, 0, stream>>>(
            h1q, fc2w_c, fc2b_c, x1 + off, d_out, off, flag);
    }
}